// Round 14
// baseline (109.080 us; speedup 1.0000x reference)
//
#include <hip/hip_runtime.h>

// MarianAttention fused pipeline for MI355X (gfx950).
// B=2, T=2048, D=1024, H=16, DH=64.
//
// Math notes (vs reference):
//  - scores are clamped to [1e-7, 1-1e-7] BEFORE softmax -> exp(S) in [1, e],
//    so no online-max is needed: l = sum(exp(S)), O = sum(exp(S) V), final O/l.
//    Post-softmax clamp and attn_out clamp are provable no-ops.
//  - exp2-domain: Q pre-scaled by 0.125*log2(e); softmax = 1 v_exp_f32/elem.
//  - no NaNs can arise from finite inputs -> nan_to_num is a no-op.
//
// R2..R13 history: swapped 32x32 MFMA attn, in-reg P via cvt_pk+permlane32,
// exp2 builtin + hoisted offsets, MFMA row-sum (parity-split) + rcp epilogue,
// XCD swizzle (attn FETCH 70->12MB), fused QKV GEMM (898 TF = m97-structure
// ceiling), gemm_out 64x128 @ 2 blocks/CU. REVERTED: R7 (1 wave/SIMD attn),
// R9 (GEMM dbuf), R10 (KVBLK=64), R11 (8-wave attn: VGPR spill).
// R14: attn micro — split oacc by kk parity (oaccE/oaccO per df), same
// proven pattern as R13's osum split; breaks the 8-long dependent PV-MFMA
// chain (dep distance 2 -> 4 issues). +32 VGPR (~156 < 256 budget).
// Component status: qkv/gemm_out at measured structure ceilings; cvt at BW
// floor; attn three-pipe balanced (MFMA 37.6 / LDS ~43 / VALU ~11%).

typedef unsigned short u16;
using bf16x8 = __attribute__((ext_vector_type(8))) __bf16;
using bf16x2 = __attribute__((ext_vector_type(2))) __bf16;
using f32x4  = __attribute__((ext_vector_type(4))) float;
using f32x16 = __attribute__((ext_vector_type(16))) float;
typedef __attribute__((ext_vector_type(2))) int v2i;
typedef __attribute__((ext_vector_type(4))) int v4i;

#define GLD16(g, l) __builtin_amdgcn_global_load_lds(                      \
    (const __attribute__((address_space(1))) void*)(g),                    \
    (__attribute__((address_space(3))) void*)(l), 16, 0, 0)

#define HIL2 1.4426949f   /* (1-1e-7) * log2(e) */

__device__ __forceinline__ float clampf(float x) {
  return fminf(fmaxf(x, 1e-7f), 0.99999988f);
}

__device__ __forceinline__ u16 f2bf(float f) {   // round-half-up f32->bf16 (no NaNs here)
  return (u16)((__float_as_uint(f) + 0x8000u) >> 16);
}

__device__ __forceinline__ int pack2(float a, float b) {  // 2 f32 -> packed bf16x2
  bf16x2 t; t[0] = (__bf16)a; t[1] = (__bf16)b;
  return __builtin_bit_cast(int, t);
}

__device__ __forceinline__ v2i plswap(int a, int b) {     // lane<32 half <-> lane>=32 half
  return __builtin_amdgcn_permlane32_swap(a, b, false, false);
}

// ---------------------------------------------------------------- converts
// One launch: y<4 -> X quarter y; y>=4 -> weight (Wq,Wk,Wv,Wo) into the
// contiguous Wall region. Each plane = 262144 float4.
__global__ __launch_bounds__(256) void cvt_all(
    const float4* __restrict__ X,
    const float4* __restrict__ w0, const float4* __restrict__ w1,
    const float4* __restrict__ w2, const float4* __restrict__ w3,
    ushort4* __restrict__ Xb, ushort4* __restrict__ Wb) {
  const int y = blockIdx.y;
  const int i = blockIdx.x * 256 + threadIdx.x;
  const float4* src;
  ushort4* dst;
  if (y < 4)      { src = X  + (size_t)y * 262144 + i; dst = Xb + (size_t)y * 262144 + i; }
  else if (y == 4){ src = w0 + i; dst = Wb + i; }
  else if (y == 5){ src = w1 + i; dst = Wb + 262144 + i; }
  else if (y == 6){ src = w2 + i; dst = Wb + 524288 + i; }
  else            { src = w3 + i; dst = Wb + 786432 + i; }
  float4 f = *src;
  ushort4 o;
  o.x = f2bf(f.x); o.y = f2bf(f.y); o.z = f2bf(f.z); o.w = f2bf(f.w);
  *dst = o;
}

// ------------------------------------------------------------- GEMM core
// C[M,N] = A[M,1024] * B[N,1024]^T ; 128x128 tile, BK=64, 4 waves (2x2),
// each wave 64x64 = 4x4 frags of 16x16x32 MFMA. m97-style 2-barrier loop.
// (Single-buffered, 32KB LDS, 3 blocks/CU cross-block TLP.)
#define GEMM_CORE(Aptr, Bptr)                                              \
  for (int k0 = 0; k0 < 1024; k0 += 64) {                                  \
    _Pragma("unroll")                                                      \
    for (int i = 0; i < 4; ++i) {                                          \
      const int lin = i * 4096 + tid * 16;                                 \
      const int row = lin >> 7;                                            \
      const int inb = lin & 127;                                           \
      GLD16(Aptr + (size_t)(m0 + row) * 1024 + k0 + (inb >> 1),            \
            (char*)sA + i * 4096 + wave * 1024);                           \
      GLD16(Bptr + (size_t)(n0 + row) * 1024 + k0 + (inb >> 1),            \
            (char*)sB + i * 4096 + wave * 1024);                           \
    }                                                                      \
    __syncthreads();                                                       \
    _Pragma("unroll")                                                      \
    for (int kk = 0; kk < 2; ++kk) {                                       \
      const int ko = kk * 32 + lg * 8;                                     \
      bf16x8 af[4], bfr[4];                                                \
      _Pragma("unroll")                                                    \
      for (int mi = 0; mi < 4; ++mi)                                       \
        af[mi] = *(const bf16x8*)(sA + (wm * 64 + mi * 16 + lr) * 64 + ko);\
      _Pragma("unroll")                                                    \
      for (int ni = 0; ni < 4; ++ni)                                       \
        bfr[ni] = *(const bf16x8*)(sB + (wn * 64 + ni * 16 + lr) * 64 + ko);\
      _Pragma("unroll")                                                    \
      for (int mi = 0; mi < 4; ++mi)                                       \
        _Pragma("unroll")                                                  \
        for (int ni = 0; ni < 4; ++ni)                                     \
          acc[mi][ni] = __builtin_amdgcn_mfma_f32_16x16x32_bf16(           \
              af[mi], bfr[ni], acc[mi][ni], 0, 0, 0);                      \
    }                                                                      \
    __syncthreads();                                                       \
  }

// Fused QKV projection: one GEMM, N = 3072 (Wall = [Wq;Wk;Wv] rows).
// p = n0>>10 selects epilogue: 0 -> Q (scale 0.125*log2e), 1 -> K,
// 2 -> V (transposed store). XCD-swizzled 1D grid (nwg=768).
__global__ __launch_bounds__(256, 3) void gemm_qkv(
    const u16* __restrict__ Xb, const u16* __restrict__ Wall,
    const float* __restrict__ bq, const float* __restrict__ bk, const float* __restrict__ bv,
    u16* __restrict__ Qo, u16* __restrict__ Ko, u16* __restrict__ Vt)
{
  __shared__ u16 sA[128 * 64];
  __shared__ u16 sB[128 * 64];
  const int tid = threadIdx.x, lane = tid & 63, wave = tid >> 6;
  const int lr = lane & 15, lg = lane >> 4;
  const int wm = wave >> 1, wn = wave & 1;
  const int bid = blockIdx.x;
  const int swz = (bid & 7) * 96 + (bid >> 3);   // nwg=768, cpx=96 (768%8==0)
  const int bx = swz % 24, by = swz / 24;
  const int n0 = bx * 128, m0 = by * 128;
  const int p = n0 >> 10;                        // uniform per block
  const float* bias = (p == 0) ? bq : (p == 1) ? bk : bv;

  f32x4 acc[4][4] = {};
  GEMM_CORE(Xb, Wall)

  if (p == 2) {
    // V: write transposed Vt[(b*16+h)*64 + dh][t]; j=0..3 consecutive t -> pack 8B
    #pragma unroll
    for (int ni = 0; ni < 4; ++ni) {
      const int n = n0 + wn * 64 + ni * 16 + lr;
      const int nloc = n & 1023;
      const float bb = bias[nloc];
      #pragma unroll
      for (int mi = 0; mi < 4; ++mi) {
        const int m = m0 + wm * 64 + mi * 16 + lg * 4;
        ushort4 pk;
        pk.x = f2bf(clampf(acc[mi][ni][0] + bb));
        pk.y = f2bf(clampf(acc[mi][ni][1] + bb));
        pk.z = f2bf(clampf(acc[mi][ni][2] + bb));
        pk.w = f2bf(clampf(acc[mi][ni][3] + bb));
        *(ushort4*)(Vt + ((size_t)((m >> 11) * 16 + (nloc >> 6)) * 64 + (nloc & 63)) * 2048
                       + (m & 2047)) = pk;
      }
    }
  } else {
    u16* O = (p == 0) ? Qo : Ko;
    const float sc  = (p == 0) ? 0.18033688f   : 1.0f;          // 0.125*log2e for Q
    const float clo = (p == 0) ? 1.4426950e-7f : 1e-7f;
    const float chi = (p == 0) ? HIL2          : 0.99999988f;
    #pragma unroll
    for (int ni = 0; ni < 4; ++ni) {
      const int n = n0 + wn * 64 + ni * 16 + lr;
      const int nloc = n & 1023;
      const float bb = bias[nloc];
      #pragma unroll
      for (int mi = 0; mi < 4; ++mi) {
        #pragma unroll
        for (int j = 0; j < 4; ++j) {
          const int m = m0 + wm * 64 + mi * 16 + lg * 4 + j;
          O[(size_t)m * 1024 + nloc] = f2bf(fminf(fmaxf((acc[mi][ni][j] + bb) * sc, clo), chi));
        }
      }
    }
  }
}

// Output projection: out = clamp(AO * Wo^T + bo), fp32 store.
// 64x128 tile -> grid 512 = 2 blocks/CU. 4 waves 2x2; wave tile 32x64.
__global__ __launch_bounds__(256, 4) void gemm_out(
    const u16* __restrict__ AOb, const u16* __restrict__ Wob,
    const float* __restrict__ bo, float* __restrict__ out)
{
  __shared__ u16 sA[64 * 64];
  __shared__ u16 sB[128 * 64];
  const int tid = threadIdx.x, lane = tid & 63, wave = tid >> 6;
  const int lr = lane & 15, lg = lane >> 4;
  const int wm = wave >> 1, wn = wave & 1;
  const int bid = blockIdx.x;
  const int swz = (bid & 7) * 64 + (bid >> 3);   // nwg=512, cpx=64
  const int bx = swz & 7, by = swz >> 3;         // bx 0..7, by 0..63
  const int n0 = bx * 128, m0 = by * 64;

  f32x4 acc[2][4] = {};
  for (int k0 = 0; k0 < 1024; k0 += 64) {
    #pragma unroll
    for (int i = 0; i < 2; ++i) {                // A tile: 64 rows
      const int lin = i * 4096 + tid * 16;
      const int row = lin >> 7;
      const int inb = lin & 127;
      GLD16(AOb + (size_t)(m0 + row) * 1024 + k0 + (inb >> 1),
            (char*)sA + i * 4096 + wave * 1024);
    }
    #pragma unroll
    for (int i = 0; i < 4; ++i) {                // B tile: 128 rows
      const int lin = i * 4096 + tid * 16;
      const int row = lin >> 7;
      const int inb = lin & 127;
      GLD16(Wob + (size_t)(n0 + row) * 1024 + k0 + (inb >> 1),
            (char*)sB + i * 4096 + wave * 1024);
    }
    __syncthreads();
    #pragma unroll
    for (int kk = 0; kk < 2; ++kk) {
      const int ko = kk * 32 + lg * 8;
      bf16x8 af[2], bfr[4];
      #pragma unroll
      for (int mi = 0; mi < 2; ++mi)
        af[mi] = *(const bf16x8*)(sA + (wm * 32 + mi * 16 + lr) * 64 + ko);
      #pragma unroll
      for (int ni = 0; ni < 4; ++ni)
        bfr[ni] = *(const bf16x8*)(sB + (wn * 64 + ni * 16 + lr) * 64 + ko);
      #pragma unroll
      for (int mi = 0; mi < 2; ++mi)
        #pragma unroll
        for (int ni = 0; ni < 4; ++ni)
          acc[mi][ni] = __builtin_amdgcn_mfma_f32_16x16x32_bf16(
              af[mi], bfr[ni], acc[mi][ni], 0, 0, 0);
    }
    __syncthreads();
  }

  #pragma unroll
  for (int ni = 0; ni < 4; ++ni) {
    const int n = n0 + wn * 64 + ni * 16 + lr;
    const float bb = bo[n];
    #pragma unroll
    for (int mi = 0; mi < 2; ++mi) {
      #pragma unroll
      for (int j = 0; j < 4; ++j) {
        const int m = m0 + wm * 32 + mi * 16 + lg * 4 + j;
        out[(size_t)m * 1024 + n] = clampf(acc[mi][ni][j] + bb);
      }
    }
  }
}

// ------------------------------------------------------------- attention
// R8 structure: one block per (128 q-rows, b*h); 4 waves; wave w owns
// q-rows [w*32, w*32+32). Swapped QK^T via 32x32x16 MFMA; P in registers;
// PV A-frag via cvt_pk + 2x permlane32_swap per 16-wide s-slice.
// l = P rowsum via MFMA (ones-B), parity-split (R13). R14: oacc also
// parity-split per df (oaccE/oaccO) to break the dependent PV-MFMA chain;
// merged at epilogue. Epilogue 1/l via v_rcp_f32. K/V double-buffered,
// x2-unrolled, precomputed offsets, carried pointers. XCD swizzle groups
// 16 q-tiles of one bh per XCD (FETCH 70->12MB measured).
__global__ __launch_bounds__(256, 2) void attn_fused(
    const u16* __restrict__ Qg, const u16* __restrict__ Kg,
    const u16* __restrict__ Vt, u16* __restrict__ AO)
{
  __shared__ u16 sK[2][128 * 64];    // [s][dh]     sw(r)=(r&7)<<3
  __shared__ u16 sV[2][64 * 128];    // [dh][s]     sw(r)=(r&15)<<3
  __shared__ u16 sQ[128 * 64];       // [qrow][dh]  sw(r)=(r&7)<<3
  const int tid = threadIdx.x, lane = tid & 63, wave = tid >> 6;
  const int lo = lane & 31, hi = lane >> 5;
  const int bid = blockIdx.x;
  const int swz = (bid & 7) * 64 + (bid >> 3);   // nwg=512, cpx=64
  const int qt = swz & 15, bh = swz >> 4;
  const int b = bh >> 4, h = bh & 15;

  // loop-carried global staging pointers (advance by one KV tile per stage)
  const u16* kgp[4];
  const u16* vgp[4];
  #pragma unroll
  for (int i = 0; i < 4; ++i) {
    const int lin = i * 4096 + tid * 16;
    const int row  = lin >> 7;
    const int colk = ((lin & 127) >> 1) ^ ((row & 7) << 3);
    kgp[i] = Kg + (size_t)(b * 2048 + row) * 1024 + h * 64 + colk;
    const int rowv = lin >> 8;
    const int colv = ((lin & 255) >> 1) ^ ((rowv & 15) << 3);
    vgp[i] = Vt + ((size_t)bh * 64 + rowv) * 2048 + colv;
  }

  // precomputed swizzled LDS byte offsets (static-indexed -> stay in VGPRs)
  int koff[4][4];   // [ks][sf]
  #pragma unroll
  for (int ks = 0; ks < 4; ++ks)
    #pragma unroll
    for (int sf = 0; sf < 4; ++sf)
      koff[ks][sf] = ((sf * 32 + lo) * 64 + ((ks * 16 + hi * 8) ^ ((lo & 7) << 3))) * 2;
  int voff[8][2];   // [kk][df]
  #pragma unroll
  for (int kk = 0; kk < 8; ++kk)
    #pragma unroll
    for (int df = 0; df < 2; ++df)
      voff[kk][df] = ((df * 32 + lo) * 128 + ((kk * 16 + hi * 8) ^ ((lo & 15) << 3))) * 2;

  // stage Q tile + KV tile 0 (buf 0)
  #pragma unroll
  for (int i = 0; i < 4; ++i) {
    const int lin = i * 4096 + tid * 16;
    const int row = lin >> 7;
    const int col = ((lin & 127) >> 1) ^ ((row & 7) << 3);
    GLD16(Qg + (size_t)(b * 2048 + qt * 128 + row) * 1024 + h * 64 + col,
          (char*)sQ + i * 4096 + wave * 1024);
    GLD16(kgp[i], (char*)sK[0] + i * 4096 + wave * 1024);
    GLD16(vgp[i], (char*)sV[0] + i * 4096 + wave * 1024);
    kgp[i] += 128 * 1024;
    vgp[i] += 128;
  }
  __syncthreads();

  // hoist this wave's Q fragments (B-operand: col=q=lo, k=8*hi+j, per 16-k step)
  bf16x8 qreg[4];
  #pragma unroll
  for (int ks = 0; ks < 4; ++ks) {
    const int row = wave * 32 + lo;
    qreg[ks] = *(const bf16x8*)(sQ + row * 64 + ((ks * 16 + hi * 8) ^ ((row & 7) << 3)));
  }

  const f32x16 zro = {};
  const v4i ones4 = {0x3F803F80, 0x3F803F80, 0x3F803F80, 0x3F803F80};
  const bf16x8 ones = __builtin_bit_cast(bf16x8, ones4);
  f32x16 oaccE[2] = {}, oaccO[2] = {};
  f32x16 osum0 = {}, osum1 = {};

  for (int tp = 0; tp < 8; ++tp) {
    #pragma unroll
    for (int half = 0; half < 2; ++half) {       // buf = half: compile-time
      const int t = tp * 2 + half;
      if (t < 15) {                              // stage tile t+1 into buf half^1
        #pragma unroll
        for (int i = 0; i < 4; ++i) {
          GLD16(kgp[i], (char*)sK[half ^ 1] + i * 4096 + wave * 1024);
          GLD16(vgp[i], (char*)sV[half ^ 1] + i * 4096 + wave * 1024);
          kgp[i] += 128 * 1024;
          vgp[i] += 128;
        }
      }
      const char* Kb = (const char*)sK[half];
      const char* Vb = (const char*)sV[half];

      // S^T = K * Q^T : A = K rows (s), B = Q rows (q). 4 s-frags x 4 k-steps.
      f32x16 sacc[4];
      __builtin_amdgcn_s_setprio(1);
      #pragma unroll
      for (int sf = 0; sf < 4; ++sf) {
        bf16x8 kf = *(const bf16x8*)(Kb + koff[0][sf]);
        sacc[sf] = __builtin_amdgcn_mfma_f32_32x32x16_bf16(kf, qreg[0], zro, 0, 0, 0);
      }
      #pragma unroll
      for (int ks = 1; ks < 4; ++ks)
        #pragma unroll
        for (int sf = 0; sf < 4; ++sf) {
          bf16x8 kf = *(const bf16x8*)(Kb + koff[ks][sf]);
          sacc[sf] = __builtin_amdgcn_mfma_f32_32x32x16_bf16(kf, qreg[ks], sacc[sf], 0, 0, 0);
        }

      // fused softmax (single v_exp_f32 per elem) + PV + MFMA row-sum
      #pragma unroll
      for (int kk = 0; kk < 8; ++kk) {
        const int sf = kk >> 1, base = (kk & 1) * 8;
        float e[8];
        #pragma unroll
        for (int r = 0; r < 8; ++r)
          e[r] = __builtin_amdgcn_exp2f(fminf(sacc[sf][base + r], HIL2));
        const int pa0 = pack2(e[0], e[1]), pa1 = pack2(e[2], e[3]);
        const int pb0 = pack2(e[4], e[5]), pb1 = pack2(e[6], e[7]);
        const v2i r0 = plswap(pa0, pb0);
        const v2i r1 = plswap(pa1, pb1);
        const v4i wv = {r0[0], r1[0], r0[1], r1[1]};
        const bf16x8 af = __builtin_bit_cast(bf16x8, wv);
        f32x16* osum = (kk & 1) ? &osum1 : &osum0;
        f32x16* oacc = (kk & 1) ? oaccO : oaccE;
        *osum = __builtin_amdgcn_mfma_f32_32x32x16_bf16(af, ones, *osum, 0, 0, 0);
        #pragma unroll
        for (int df = 0; df < 2; ++df) {
          bf16x8 vf = *(const bf16x8*)(Vb + voff[kk][df]);
          oacc[df] = __builtin_amdgcn_mfma_f32_32x32x16_bf16(af, vf, oacc[df], 0, 0, 0);
        }
      }
      __builtin_amdgcn_s_setprio(0);
      __syncthreads();
    }
  }

  // epilogue: merge parity halves; osum[reg] is l for the same q-row as
  // oacc[df][reg] -> divide directly (rcp: l in [128, 2048e], 1-ulp ok)
  const f32x16 osum = osum0 + osum1;
  const f32x16 oacc0 = oaccE[0] + oaccO[0];
  const f32x16 oacc1 = oaccE[1] + oaccO[1];
  #pragma unroll
  for (int g = 0; g < 4; ++g) {
    #pragma unroll
    for (int r = 0; r < 4; ++r) {
      const float iv = __builtin_amdgcn_rcpf(osum[g * 4 + r]);
      const int m = qt * 128 + wave * 32 + hi * 4 + g * 8 + r;
      const float v0 = oacc0[g * 4 + r] * iv;
      const float v1 = oacc1[g * 4 + r] * iv;
      AO[(size_t)(b * 2048 + m) * 1024 + h * 64 + lo]      = f2bf(clampf(v0));
      AO[(size_t)(b * 2048 + m) * 1024 + h * 64 + 32 + lo] = f2bf(clampf(v1));
    }
  }
}

// ---------------------------------------------------------------- launch
extern "C" void kernel_launch(void* const* d_in, const int* in_sizes, int n_in,
                              void* d_out, int out_size, void* d_ws, size_t ws_size,
                              hipStream_t stream) {
  const float* X  = (const float*)d_in[0];
  const float* Wq = (const float*)d_in[1];
  const float* bq = (const float*)d_in[2];
  const float* Wk = (const float*)d_in[3];
  const float* bk = (const float*)d_in[4];
  const float* Wv = (const float*)d_in[5];
  const float* bv = (const float*)d_in[6];
  const float* Wo = (const float*)d_in[7];
  const float* bo = (const float*)d_in[8];
  float* out = (float*)d_out;

  if (ws_size < (size_t)48 * 1024 * 1024) return;  // fail loudly (output stays poisoned)

  u16* ws  = (u16*)d_ws;
  u16* Xb  = ws;                         // [4096][1024]  8 MB
  u16* Wall= ws + (size_t)4  * 1048576;  // [3072][1024]  6 MB  (Wq;Wk;Wv)
  u16* Wob = ws + (size_t)7  * 1048576;  // [1024][1024]  2 MB
  u16* Qb  = ws + (size_t)8  * 1048576;  // [4096][1024]  8 MB
  u16* Kb  = ws + (size_t)12 * 1048576;
  u16* Vtb = ws + (size_t)16 * 1048576;  // [32][64][2048] 8 MB
  u16* AOb = ws + (size_t)20 * 1048576;  // [4096][1024]  8 MB

  cvt_all<<<dim3(1024, 8), 256, 0, stream>>>(
      (const float4*)X, (const float4*)Wq, (const float4*)Wk,
      (const float4*)Wv, (const float4*)Wo, (ushort4*)Xb, (ushort4*)Wall);

  gemm_qkv<<<768, 256, 0, stream>>>(Xb, Wall, bq, bk, bv, Qb, Kb, Vtb);
  attn_fused<<<512, 256, 0, stream>>>(Qb, Kb, Vtb, AOb);
  gemm_out<<<512, 256, 0, stream>>>(AOb, Wob, bo, out);
}

// Round 15
// 107.246 us; speedup vs baseline: 1.0171x; 1.0171x over previous
//
#include <hip/hip_runtime.h>

// MarianAttention fused pipeline for MI355X (gfx950).
// B=2, T=2048, D=1024, H=16, DH=64.
//
// Math notes (vs reference):
//  - scores are clamped to [1e-7, 1-1e-7] BEFORE softmax -> exp(S) in [1, e],
//    so no online-max is needed: l = sum(exp(S)), O = sum(exp(S) V), final O/l.
//    Post-softmax clamp and attn_out clamp are provable no-ops.
//  - exp2-domain: Q pre-scaled by 0.125*log2(e); softmax = 1 v_exp_f32/elem.
//  - no NaNs can arise from finite inputs -> nan_to_num is a no-op.
//
// FINAL FORM (= R13, best measured 107.5us):
//  - cvt_all: one launch, 48MB at ~6.3TB/s achievable BW (memory roofline).
//  - gemm_qkv: fused N=3072 m97-structure GEMM, 898 TF = structure ceiling
//    (m103: 912 TF), 3 blocks/CU, XCD-swizzled.
//  - attn: swapped 32x32x16 MFMA (S^T=K*Q^T), P in registers via
//    cvt_pk+permlane32_swap, exp2-domain softmax (1 v_exp/elem), MFMA
//    row-sum (parity-split) + rcp epilogue, K/V dbuf, XCD swizzle
//    (FETCH 70->12MB). Three-pipe balanced: MFMA 37.6/LDS ~43/VALU ~11%.
//  - gemm_out: 64x128 tile, 2 blocks/CU, 860 TF.
// REVERTED experiments: R7 (1 wave/SIMD), R9 (GEMM dbuf), R10 (KVBLK=64),
// R11 (8-wave attn: spill), R14 (oacc parity-split: broke R13's schedule).

typedef unsigned short u16;
using bf16x8 = __attribute__((ext_vector_type(8))) __bf16;
using bf16x2 = __attribute__((ext_vector_type(2))) __bf16;
using f32x4  = __attribute__((ext_vector_type(4))) float;
using f32x16 = __attribute__((ext_vector_type(16))) float;
typedef __attribute__((ext_vector_type(2))) int v2i;
typedef __attribute__((ext_vector_type(4))) int v4i;

#define GLD16(g, l) __builtin_amdgcn_global_load_lds(                      \
    (const __attribute__((address_space(1))) void*)(g),                    \
    (__attribute__((address_space(3))) void*)(l), 16, 0, 0)

#define HIL2 1.4426949f   /* (1-1e-7) * log2(e) */

__device__ __forceinline__ float clampf(float x) {
  return fminf(fmaxf(x, 1e-7f), 0.99999988f);
}

__device__ __forceinline__ u16 f2bf(float f) {   // round-half-up f32->bf16 (no NaNs here)
  return (u16)((__float_as_uint(f) + 0x8000u) >> 16);
}

__device__ __forceinline__ int pack2(float a, float b) {  // 2 f32 -> packed bf16x2
  bf16x2 t; t[0] = (__bf16)a; t[1] = (__bf16)b;
  return __builtin_bit_cast(int, t);
}

__device__ __forceinline__ v2i plswap(int a, int b) {     // lane<32 half <-> lane>=32 half
  return __builtin_amdgcn_permlane32_swap(a, b, false, false);
}

// ---------------------------------------------------------------- converts
// One launch: y<4 -> X quarter y; y>=4 -> weight (Wq,Wk,Wv,Wo) into the
// contiguous Wall region. Each plane = 262144 float4.
__global__ __launch_bounds__(256) void cvt_all(
    const float4* __restrict__ X,
    const float4* __restrict__ w0, const float4* __restrict__ w1,
    const float4* __restrict__ w2, const float4* __restrict__ w3,
    ushort4* __restrict__ Xb, ushort4* __restrict__ Wb) {
  const int y = blockIdx.y;
  const int i = blockIdx.x * 256 + threadIdx.x;
  const float4* src;
  ushort4* dst;
  if (y < 4)      { src = X  + (size_t)y * 262144 + i; dst = Xb + (size_t)y * 262144 + i; }
  else if (y == 4){ src = w0 + i; dst = Wb + i; }
  else if (y == 5){ src = w1 + i; dst = Wb + 262144 + i; }
  else if (y == 6){ src = w2 + i; dst = Wb + 524288 + i; }
  else            { src = w3 + i; dst = Wb + 786432 + i; }
  float4 f = *src;
  ushort4 o;
  o.x = f2bf(f.x); o.y = f2bf(f.y); o.z = f2bf(f.z); o.w = f2bf(f.w);
  *dst = o;
}

// ------------------------------------------------------------- GEMM core
// C[M,N] = A[M,1024] * B[N,1024]^T ; 128x128 tile, BK=64, 4 waves (2x2),
// each wave 64x64 = 4x4 frags of 16x16x32 MFMA. m97-style 2-barrier loop.
// (Single-buffered, 32KB LDS, 3 blocks/CU cross-block TLP.)
#define GEMM_CORE(Aptr, Bptr)                                              \
  for (int k0 = 0; k0 < 1024; k0 += 64) {                                  \
    _Pragma("unroll")                                                      \
    for (int i = 0; i < 4; ++i) {                                          \
      const int lin = i * 4096 + tid * 16;                                 \
      const int row = lin >> 7;                                            \
      const int inb = lin & 127;                                           \
      GLD16(Aptr + (size_t)(m0 + row) * 1024 + k0 + (inb >> 1),            \
            (char*)sA + i * 4096 + wave * 1024);                           \
      GLD16(Bptr + (size_t)(n0 + row) * 1024 + k0 + (inb >> 1),            \
            (char*)sB + i * 4096 + wave * 1024);                           \
    }                                                                      \
    __syncthreads();                                                       \
    _Pragma("unroll")                                                      \
    for (int kk = 0; kk < 2; ++kk) {                                       \
      const int ko = kk * 32 + lg * 8;                                     \
      bf16x8 af[4], bfr[4];                                                \
      _Pragma("unroll")                                                    \
      for (int mi = 0; mi < 4; ++mi)                                       \
        af[mi] = *(const bf16x8*)(sA + (wm * 64 + mi * 16 + lr) * 64 + ko);\
      _Pragma("unroll")                                                    \
      for (int ni = 0; ni < 4; ++ni)                                       \
        bfr[ni] = *(const bf16x8*)(sB + (wn * 64 + ni * 16 + lr) * 64 + ko);\
      _Pragma("unroll")                                                    \
      for (int mi = 0; mi < 4; ++mi)                                       \
        _Pragma("unroll")                                                  \
        for (int ni = 0; ni < 4; ++ni)                                     \
          acc[mi][ni] = __builtin_amdgcn_mfma_f32_16x16x32_bf16(           \
              af[mi], bfr[ni], acc[mi][ni], 0, 0, 0);                      \
    }                                                                      \
    __syncthreads();                                                       \
  }

// Fused QKV projection: one GEMM, N = 3072 (Wall = [Wq;Wk;Wv] rows).
// p = n0>>10 selects epilogue: 0 -> Q (scale 0.125*log2e), 1 -> K,
// 2 -> V (transposed store). XCD-swizzled 1D grid (nwg=768).
__global__ __launch_bounds__(256, 3) void gemm_qkv(
    const u16* __restrict__ Xb, const u16* __restrict__ Wall,
    const float* __restrict__ bq, const float* __restrict__ bk, const float* __restrict__ bv,
    u16* __restrict__ Qo, u16* __restrict__ Ko, u16* __restrict__ Vt)
{
  __shared__ u16 sA[128 * 64];
  __shared__ u16 sB[128 * 64];
  const int tid = threadIdx.x, lane = tid & 63, wave = tid >> 6;
  const int lr = lane & 15, lg = lane >> 4;
  const int wm = wave >> 1, wn = wave & 1;
  const int bid = blockIdx.x;
  const int swz = (bid & 7) * 96 + (bid >> 3);   // nwg=768, cpx=96 (768%8==0)
  const int bx = swz % 24, by = swz / 24;
  const int n0 = bx * 128, m0 = by * 128;
  const int p = n0 >> 10;                        // uniform per block
  const float* bias = (p == 0) ? bq : (p == 1) ? bk : bv;

  f32x4 acc[4][4] = {};
  GEMM_CORE(Xb, Wall)

  if (p == 2) {
    // V: write transposed Vt[(b*16+h)*64 + dh][t]; j=0..3 consecutive t -> pack 8B
    #pragma unroll
    for (int ni = 0; ni < 4; ++ni) {
      const int n = n0 + wn * 64 + ni * 16 + lr;
      const int nloc = n & 1023;
      const float bb = bias[nloc];
      #pragma unroll
      for (int mi = 0; mi < 4; ++mi) {
        const int m = m0 + wm * 64 + mi * 16 + lg * 4;
        ushort4 pk;
        pk.x = f2bf(clampf(acc[mi][ni][0] + bb));
        pk.y = f2bf(clampf(acc[mi][ni][1] + bb));
        pk.z = f2bf(clampf(acc[mi][ni][2] + bb));
        pk.w = f2bf(clampf(acc[mi][ni][3] + bb));
        *(ushort4*)(Vt + ((size_t)((m >> 11) * 16 + (nloc >> 6)) * 64 + (nloc & 63)) * 2048
                       + (m & 2047)) = pk;
      }
    }
  } else {
    u16* O = (p == 0) ? Qo : Ko;
    const float sc  = (p == 0) ? 0.18033688f   : 1.0f;          // 0.125*log2e for Q
    const float clo = (p == 0) ? 1.4426950e-7f : 1e-7f;
    const float chi = (p == 0) ? HIL2          : 0.99999988f;
    #pragma unroll
    for (int ni = 0; ni < 4; ++ni) {
      const int n = n0 + wn * 64 + ni * 16 + lr;
      const int nloc = n & 1023;
      const float bb = bias[nloc];
      #pragma unroll
      for (int mi = 0; mi < 4; ++mi) {
        #pragma unroll
        for (int j = 0; j < 4; ++j) {
          const int m = m0 + wm * 64 + mi * 16 + lg * 4 + j;
          O[(size_t)m * 1024 + nloc] = f2bf(fminf(fmaxf((acc[mi][ni][j] + bb) * sc, clo), chi));
        }
      }
    }
  }
}

// Output projection: out = clamp(AO * Wo^T + bo), fp32 store.
// 64x128 tile -> grid 512 = 2 blocks/CU. 4 waves 2x2; wave tile 32x64.
__global__ __launch_bounds__(256, 4) void gemm_out(
    const u16* __restrict__ AOb, const u16* __restrict__ Wob,
    const float* __restrict__ bo, float* __restrict__ out)
{
  __shared__ u16 sA[64 * 64];
  __shared__ u16 sB[128 * 64];
  const int tid = threadIdx.x, lane = tid & 63, wave = tid >> 6;
  const int lr = lane & 15, lg = lane >> 4;
  const int wm = wave >> 1, wn = wave & 1;
  const int bid = blockIdx.x;
  const int swz = (bid & 7) * 64 + (bid >> 3);   // nwg=512, cpx=64
  const int bx = swz & 7, by = swz >> 3;         // bx 0..7, by 0..63
  const int n0 = bx * 128, m0 = by * 64;

  f32x4 acc[2][4] = {};
  for (int k0 = 0; k0 < 1024; k0 += 64) {
    #pragma unroll
    for (int i = 0; i < 2; ++i) {                // A tile: 64 rows
      const int lin = i * 4096 + tid * 16;
      const int row = lin >> 7;
      const int inb = lin & 127;
      GLD16(AOb + (size_t)(m0 + row) * 1024 + k0 + (inb >> 1),
            (char*)sA + i * 4096 + wave * 1024);
    }
    #pragma unroll
    for (int i = 0; i < 4; ++i) {                // B tile: 128 rows
      const int lin = i * 4096 + tid * 16;
      const int row = lin >> 7;
      const int inb = lin & 127;
      GLD16(Wob + (size_t)(n0 + row) * 1024 + k0 + (inb >> 1),
            (char*)sB + i * 4096 + wave * 1024);
    }
    __syncthreads();
    #pragma unroll
    for (int kk = 0; kk < 2; ++kk) {
      const int ko = kk * 32 + lg * 8;
      bf16x8 af[2], bfr[4];
      #pragma unroll
      for (int mi = 0; mi < 2; ++mi)
        af[mi] = *(const bf16x8*)(sA + (wm * 32 + mi * 16 + lr) * 64 + ko);
      #pragma unroll
      for (int ni = 0; ni < 4; ++ni)
        bfr[ni] = *(const bf16x8*)(sB + (wn * 64 + ni * 16 + lr) * 64 + ko);
      #pragma unroll
      for (int mi = 0; mi < 2; ++mi)
        #pragma unroll
        for (int ni = 0; ni < 4; ++ni)
          acc[mi][ni] = __builtin_amdgcn_mfma_f32_16x16x32_bf16(
              af[mi], bfr[ni], acc[mi][ni], 0, 0, 0);
    }
    __syncthreads();
  }

  #pragma unroll
  for (int ni = 0; ni < 4; ++ni) {
    const int n = n0 + wn * 64 + ni * 16 + lr;
    const float bb = bo[n];
    #pragma unroll
    for (int mi = 0; mi < 2; ++mi) {
      #pragma unroll
      for (int j = 0; j < 4; ++j) {
        const int m = m0 + wm * 32 + mi * 16 + lg * 4 + j;
        out[(size_t)m * 1024 + n] = clampf(acc[mi][ni][j] + bb);
      }
    }
  }
}

// ------------------------------------------------------------- attention
// R8 structure: one block per (128 q-rows, b*h); 4 waves; wave w owns
// q-rows [w*32, w*32+32). Swapped QK^T via 32x32x16 MFMA; P in registers;
// PV A-frag via cvt_pk + 2x permlane32_swap per 16-wide s-slice.
// l = P rowsum via MFMA (ones-B), R13: split across osum0/osum1 by kk
// parity to break the dependent-MFMA chain; merged once at epilogue.
// Epilogue 1/l via v_rcp_f32 (R13). K/V double-buffered, x2-unrolled,
// precomputed offsets, carried pointers. XCD swizzle groups 16 q-tiles of
// one bh per XCD (FETCH 70->12MB measured).
__global__ __launch_bounds__(256, 2) void attn_fused(
    const u16* __restrict__ Qg, const u16* __restrict__ Kg,
    const u16* __restrict__ Vt, u16* __restrict__ AO)
{
  __shared__ u16 sK[2][128 * 64];    // [s][dh]     sw(r)=(r&7)<<3
  __shared__ u16 sV[2][64 * 128];    // [dh][s]     sw(r)=(r&15)<<3
  __shared__ u16 sQ[128 * 64];       // [qrow][dh]  sw(r)=(r&7)<<3
  const int tid = threadIdx.x, lane = tid & 63, wave = tid >> 6;
  const int lo = lane & 31, hi = lane >> 5;
  const int bid = blockIdx.x;
  const int swz = (bid & 7) * 64 + (bid >> 3);   // nwg=512, cpx=64
  const int qt = swz & 15, bh = swz >> 4;
  const int b = bh >> 4, h = bh & 15;

  // loop-carried global staging pointers (advance by one KV tile per stage)
  const u16* kgp[4];
  const u16* vgp[4];
  #pragma unroll
  for (int i = 0; i < 4; ++i) {
    const int lin = i * 4096 + tid * 16;
    const int row  = lin >> 7;
    const int colk = ((lin & 127) >> 1) ^ ((row & 7) << 3);
    kgp[i] = Kg + (size_t)(b * 2048 + row) * 1024 + h * 64 + colk;
    const int rowv = lin >> 8;
    const int colv = ((lin & 255) >> 1) ^ ((rowv & 15) << 3);
    vgp[i] = Vt + ((size_t)bh * 64 + rowv) * 2048 + colv;
  }

  // precomputed swizzled LDS byte offsets (static-indexed -> stay in VGPRs)
  int koff[4][4];   // [ks][sf]
  #pragma unroll
  for (int ks = 0; ks < 4; ++ks)
    #pragma unroll
    for (int sf = 0; sf < 4; ++sf)
      koff[ks][sf] = ((sf * 32 + lo) * 64 + ((ks * 16 + hi * 8) ^ ((lo & 7) << 3))) * 2;
  int voff[8][2];   // [kk][df]
  #pragma unroll
  for (int kk = 0; kk < 8; ++kk)
    #pragma unroll
    for (int df = 0; df < 2; ++df)
      voff[kk][df] = ((df * 32 + lo) * 128 + ((kk * 16 + hi * 8) ^ ((lo & 15) << 3))) * 2;

  // stage Q tile + KV tile 0 (buf 0)
  #pragma unroll
  for (int i = 0; i < 4; ++i) {
    const int lin = i * 4096 + tid * 16;
    const int row = lin >> 7;
    const int col = ((lin & 127) >> 1) ^ ((row & 7) << 3);
    GLD16(Qg + (size_t)(b * 2048 + qt * 128 + row) * 1024 + h * 64 + col,
          (char*)sQ + i * 4096 + wave * 1024);
    GLD16(kgp[i], (char*)sK[0] + i * 4096 + wave * 1024);
    GLD16(vgp[i], (char*)sV[0] + i * 4096 + wave * 1024);
    kgp[i] += 128 * 1024;
    vgp[i] += 128;
  }
  __syncthreads();

  // hoist this wave's Q fragments (B-operand: col=q=lo, k=8*hi+j, per 16-k step)
  bf16x8 qreg[4];
  #pragma unroll
  for (int ks = 0; ks < 4; ++ks) {
    const int row = wave * 32 + lo;
    qreg[ks] = *(const bf16x8*)(sQ + row * 64 + ((ks * 16 + hi * 8) ^ ((row & 7) << 3)));
  }

  const f32x16 zro = {};
  const v4i ones4 = {0x3F803F80, 0x3F803F80, 0x3F803F80, 0x3F803F80};
  const bf16x8 ones = __builtin_bit_cast(bf16x8, ones4);
  f32x16 oacc[2] = {};
  f32x16 osum0 = {}, osum1 = {};

  for (int tp = 0; tp < 8; ++tp) {
    #pragma unroll
    for (int half = 0; half < 2; ++half) {       // buf = half: compile-time
      const int t = tp * 2 + half;
      if (t < 15) {                              // stage tile t+1 into buf half^1
        #pragma unroll
        for (int i = 0; i < 4; ++i) {
          GLD16(kgp[i], (char*)sK[half ^ 1] + i * 4096 + wave * 1024);
          GLD16(vgp[i], (char*)sV[half ^ 1] + i * 4096 + wave * 1024);
          kgp[i] += 128 * 1024;
          vgp[i] += 128;
        }
      }
      const char* Kb = (const char*)sK[half];
      const char* Vb = (const char*)sV[half];

      // S^T = K * Q^T : A = K rows (s), B = Q rows (q). 4 s-frags x 4 k-steps.
      f32x16 sacc[4];
      __builtin_amdgcn_s_setprio(1);
      #pragma unroll
      for (int sf = 0; sf < 4; ++sf) {
        bf16x8 kf = *(const bf16x8*)(Kb + koff[0][sf]);
        sacc[sf] = __builtin_amdgcn_mfma_f32_32x32x16_bf16(kf, qreg[0], zro, 0, 0, 0);
      }
      #pragma unroll
      for (int ks = 1; ks < 4; ++ks)
        #pragma unroll
        for (int sf = 0; sf < 4; ++sf) {
          bf16x8 kf = *(const bf16x8*)(Kb + koff[ks][sf]);
          sacc[sf] = __builtin_amdgcn_mfma_f32_32x32x16_bf16(kf, qreg[ks], sacc[sf], 0, 0, 0);
        }

      // fused softmax (single v_exp_f32 per elem) + PV + MFMA row-sum
      #pragma unroll
      for (int kk = 0; kk < 8; ++kk) {
        const int sf = kk >> 1, base = (kk & 1) * 8;
        float e[8];
        #pragma unroll
        for (int r = 0; r < 8; ++r)
          e[r] = __builtin_amdgcn_exp2f(fminf(sacc[sf][base + r], HIL2));
        const int pa0 = pack2(e[0], e[1]), pa1 = pack2(e[2], e[3]);
        const int pb0 = pack2(e[4], e[5]), pb1 = pack2(e[6], e[7]);
        const v2i r0 = plswap(pa0, pb0);
        const v2i r1 = plswap(pa1, pb1);
        const v4i wv = {r0[0], r1[0], r0[1], r1[1]};
        const bf16x8 af = __builtin_bit_cast(bf16x8, wv);
        if (kk & 1)
          osum1 = __builtin_amdgcn_mfma_f32_32x32x16_bf16(af, ones, osum1, 0, 0, 0);
        else
          osum0 = __builtin_amdgcn_mfma_f32_32x32x16_bf16(af, ones, osum0, 0, 0, 0);
        #pragma unroll
        for (int df = 0; df < 2; ++df) {
          bf16x8 vf = *(const bf16x8*)(Vb + voff[kk][df]);
          oacc[df] = __builtin_amdgcn_mfma_f32_32x32x16_bf16(af, vf, oacc[df], 0, 0, 0);
        }
      }
      __builtin_amdgcn_s_setprio(0);
      __syncthreads();
    }
  }

  // epilogue: osum[reg] is l for the same q-row as oacc[df][reg] -> divide directly
  const f32x16 osum = osum0 + osum1;
  #pragma unroll
  for (int g = 0; g < 4; ++g) {
    #pragma unroll
    for (int r = 0; r < 4; ++r) {
      const float iv = __builtin_amdgcn_rcpf(osum[g * 4 + r]);
      const int m = qt * 128 + wave * 32 + hi * 4 + g * 8 + r;
      #pragma unroll
      for (int df = 0; df < 2; ++df) {
        const float v = oacc[df][g * 4 + r] * iv;
        AO[(size_t)(b * 2048 + m) * 1024 + h * 64 + df * 32 + lo] = f2bf(clampf(v));
      }
    }
  }
}

// ---------------------------------------------------------------- launch
extern "C" void kernel_launch(void* const* d_in, const int* in_sizes, int n_in,
                              void* d_out, int out_size, void* d_ws, size_t ws_size,
                              hipStream_t stream) {
  const float* X  = (const float*)d_in[0];
  const float* Wq = (const float*)d_in[1];
  const float* bq = (const float*)d_in[2];
  const float* Wk = (const float*)d_in[3];
  const float* bk = (const float*)d_in[4];
  const float* Wv = (const float*)d_in[5];
  const float* bv = (const float*)d_in[6];
  const float* Wo = (const float*)d_in[7];
  const float* bo = (const float*)d_in[8];
  float* out = (float*)d_out;

  if (ws_size < (size_t)48 * 1024 * 1024) return;  // fail loudly (output stays poisoned)

  u16* ws  = (u16*)d_ws;
  u16* Xb  = ws;                         // [4096][1024]  8 MB
  u16* Wall= ws + (size_t)4  * 1048576;  // [3072][1024]  6 MB  (Wq;Wk;Wv)
  u16* Wob = ws + (size_t)7  * 1048576;  // [1024][1024]  2 MB
  u16* Qb  = ws + (size_t)8  * 1048576;  // [4096][1024]  8 MB
  u16* Kb  = ws + (size_t)12 * 1048576;
  u16* Vtb = ws + (size_t)16 * 1048576;  // [32][64][2048] 8 MB
  u16* AOb = ws + (size_t)20 * 1048576;  // [4096][1024]  8 MB

  cvt_all<<<dim3(1024, 8), 256, 0, stream>>>(
      (const float4*)X, (const float4*)Wq, (const float4*)Wk,
      (const float4*)Wv, (const float4*)Wo, (ushort4*)Xb, (ushort4*)Wall);

  gemm_qkv<<<768, 256, 0, stream>>>(Xb, Wall, bq, bk, bv, Qb, Kb, Vtb);
  attn_fused<<<512, 256, 0, stream>>>(Qb, Kb, Vtb, AOb);
  gemm_out<<<512, 256, 0, stream>>>(AOb, Wob, bo, out);
}